// Round 5
// baseline (197.805 us; speedup 1.0000x reference)
//
#include <hip/hip_runtime.h>

// Balloon-Windkessel BOLD, explicit Euler, T=1000, B=16384.
// alpha==1 decouples the system: (s,f) is an affine scan with constant 2x2
// matrix A; v,q are affine scans with constant scalar av = 1-DT/lamb. Only
// E(f) is nonlinear (pointwise). Parallelize T:
//   40 chunks x 25 steps; block = 16 sims x 40 chunks = 640 threads.
//   P1: per-chunk (s,f) affine aggregate            (stream z)
//   scan1 (LDS, Hillis-Steele, A^(25*2^j), 6 lvls)  -> chunk-start (s,f)
//   P2: replay chunk f_t, accumulate v,q aggregates (re-stream z, L3-hot)
//   scan2 (scalar av^(25*2^j))                      -> chunk-start (v,q)
//   P3: replay, compute y, NT store                 (re-stream z)
//
// ROUND-5 RATIONALE: r0/r1/r3/r4 all show ~17us of VALU-busy time and
// ~30us of stall, with HBM<=43%, issue-rate cuts neutral, conflicts 0.
// The shared limiter: 20 waves/CU (5/SIMD) -> too few waves to cover
// lgkmcnt/vmcnt/barrier stalls. This version keeps the best-measured
// structure (r0 streaming replay; staging/LDS-tile variants were SLOWER)
// and raises TLP: GSIMS=16 -> grid 1024 -> 3 blocks/CU = 30 waves/CU.
// LDS = 5 KB (scan arrays only). launch_bounds(640,8) caps VGPR at 64.
// Chunk-power matrices computed once in f64 keep chunk-start rounding
// ~1e-6; P2/P3 replay f with IDENTICAL ops so v,q see one consistent f.

#define BATCH     16384
#define DT        0.01f
#define NOISE_AMP 0.01f
#define V0        0.02f
#define CHUNKS    40
#define CL        25          // 40 * 25 = 1000 steps
#define LANES     16          // lanes (sims) per chunk-row
#define GSIMS     16          // sims per block
#define NTHREADS  (CHUNKS * LANES)   // 640
#define LEVELS    6           // ceil(log2(40))

#if __has_builtin(__builtin_amdgcn_exp2f)
#define EXP2F(x) __builtin_amdgcn_exp2f(x)
#else
#define EXP2F(x) exp2f(x)
#endif

__device__ __forceinline__ float uf(float x) {
    return __uint_as_float(__builtin_amdgcn_readfirstlane(__float_as_uint(x)));
}

struct D22 { double a, b, c, d; };
__device__ __forceinline__ D22 dmul(D22 x, D22 y) {
    D22 r;
    r.a = x.a * y.a + x.b * y.c;  r.b = x.a * y.b + x.b * y.d;
    r.c = x.c * y.a + x.d * y.c;  r.d = x.c * y.b + x.d * y.d;
    return r;
}

__global__ __launch_bounds__(NTHREADS, 8) void balloon_scan(
    const float* __restrict__ noise,
    const float* __restrict__ p_sigma,
    const float* __restrict__ p_mu,
    const float* __restrict__ p_lamb,
    const float* __restrict__ p_beta,
    const float* __restrict__ p_psi,
    const float* __restrict__ p_phi,
    const float* __restrict__ p_chi,
    float* __restrict__ out)
{
    const int tid = threadIdx.x;
    const int g   = tid & (LANES - 1);   // sim within block
    const int cc  = tid >> 4;            // chunk 0..39
    const int sim = blockIdx.x * GSIMS + g;

    const float sigma = uf(p_sigma[0]);
    const float mu    = uf(p_mu[0]);
    const float lamb  = uf(p_lamb[0]);
    const float beta  = uf(p_beta[0]);
    const float psi   = uf(p_psi[0]);
    const float phi   = uf(p_phi[0]);
    const float chi   = uf(p_chi[0]);

    // ---- uniform fp32 step constants (identical forms to the validated R2) ----
    const float as_   = 1.0f - DT * sigma;
    const float dtn   = DT * NOISE_AMP;
    const float dtm   = DT * mu;
    const float dt_il = uf((float)(0.01 / (double)lamb));
    const float av    = 1.0f - dt_il;
    const float kq    = uf(dt_il / beta);
    const float lc    = uf(log2f(1.0f - beta));
    const float c0 = V0 * (phi + psi + chi), c1 = V0 * phi, c2 = V0 * psi, c3 = V0 * chi;

    // ---- chunk-power weights in f64, once: A^(25*2^j), av^(25*2^j) ----
    D22 A; A.a = 1.0 - 0.01 * (double)sigma; A.b = -0.01 * (double)mu;
           A.c = 0.01;                       A.d = 1.0;
    D22 A2 = dmul(A, A), A4 = dmul(A2, A2), A8 = dmul(A4, A4);
    D22 A16 = dmul(A8, A8);
    D22 P = dmul(dmul(A16, A8), A);                 // A^25
    double avd = 1.0 - 0.01 / (double)lamb;
    double av2 = avd * avd, av4 = av2 * av2, av8 = av4 * av4;
    double av16 = av8 * av8;
    double ap = av16 * av8 * avd;                   // av^25

    float M11[LEVELS], M12[LEVELS], M21[LEVELS], M22[LEVELS], AVP[LEVELS];
#pragma unroll
    for (int j = 0; j < LEVELS; ++j) {
        M11[j] = uf((float)P.a); M12[j] = uf((float)P.b);
        M21[j] = uf((float)P.c); M22[j] = uf((float)P.d);
        AVP[j] = uf((float)ap);
        P = dmul(P, P); ap = ap * ap;
    }

    // homogeneous parts at this thread's chunk start: A^(25c)*(0,1), av^(25c)*1
    float ws = 0.0f, wf = 1.0f, avc = 1.0f;
#pragma unroll
    for (int j = 0; j < LEVELS; ++j) {
        if ((cc >> j) & 1) {
            float t = __builtin_fmaf(M11[j], ws, M12[j] * wf);
            wf = __builtin_fmaf(M21[j], ws, M22[j] * wf);
            ws = t;
            avc *= AVP[j];
        }
    }

    __shared__ float sA[NTHREADS];
    __shared__ float sB[NTHREADS];

    const float* zp = noise + cc * (CL * BATCH) + sim;

    // ---------------- P1: (s,f) chunk aggregate ----------------
    float rs = 0.0f, rf = 0.0f;
#pragma unroll
    for (int j = 0; j < CL; ++j) {
        const float z = zp[j * BATCH];
        const float u = __builtin_fmaf(dtn, z, dtm);
        const float t = __builtin_fmaf(as_, rs, __builtin_fmaf(-dtm, rf, u));
        rf = __builtin_fmaf(DT, rs, rf);
        rs = t;
    }

    // ---------------- scan1: inclusive over chunks, matrix weights ----------------
    sA[tid] = rs; sB[tid] = rf;
    __syncthreads();
#pragma unroll
    for (int j = 0; j < LEVELS; ++j) {
        const int off = 1 << j;
        float ns = 0.0f, nf = 0.0f;
        const bool has = (cc >= off);
        if (has) { ns = sA[tid - off * LANES]; nf = sB[tid - off * LANES]; }
        __syncthreads();
        if (has) {
            rs = __builtin_fmaf(M11[j], ns, __builtin_fmaf(M12[j], nf, rs));
            rf = __builtin_fmaf(M21[j], ns, __builtin_fmaf(M22[j], nf, rf));
            sA[tid] = rs; sB[tid] = rf;
        }
        __syncthreads();
    }
    float s0 = ws, f0 = wf;
    if (cc > 0) { s0 += sA[tid - LANES]; f0 += sB[tid - LANES]; }
    __syncthreads();   // sA/sB reads done; safe to reuse for scan2

    // ---------------- P2: replay f, accumulate v,q aggregates ----------------
    float s = s0, f = f0, Rv = 0.0f, Rq = 0.0f;
#pragma unroll
    for (int j = 0; j < CL; ++j) {
        const float z    = zp[j * BATCH];
        const float invf = __builtin_amdgcn_rcpf(f);
        const float e2   = EXP2F(lc * invf);
        const float t1   = __builtin_fmaf(-f, e2, f);       // f*E(f)
        Rv = __builtin_fmaf(av, Rv, dt_il * f);
        Rq = __builtin_fmaf(av, Rq, kq * t1);
        // canonical (s,f) step — MUST match P3 exactly
        const float s2 = __builtin_fmaf(as_, s,
                         __builtin_fmaf(dtn, z,
                         __builtin_fmaf(-dtm, f, dtm)));
        f = __builtin_fmaf(DT, s, f);
        s = s2;
    }

    // ---------------- scan2: scalar weights av^(25*2^j) ----------------
    sA[tid] = Rv; sB[tid] = Rq;
    __syncthreads();
#pragma unroll
    for (int j = 0; j < LEVELS; ++j) {
        const int off = 1 << j;
        float nv = 0.0f, nq = 0.0f;
        const bool has = (cc >= off);
        if (has) { nv = sA[tid - off * LANES]; nq = sB[tid - off * LANES]; }
        __syncthreads();
        if (has) {
            Rv = __builtin_fmaf(AVP[j], nv, Rv);
            Rq = __builtin_fmaf(AVP[j], nq, Rq);
            sA[tid] = Rv; sB[tid] = Rq;
        }
        __syncthreads();
    }
    float v = avc, q = avc;                 // v0 = q0 = 1
    if (cc > 0) { v += sA[tid - LANES]; q += sB[tid - LANES]; }

    // ---------------- P3: replay, compute y, NT store ----------------
    s = s0; f = f0;
    float* op = out + cc * (CL * BATCH) + sim;
#pragma unroll
    for (int j = 0; j < CL; ++j) {
        const float z    = zp[j * BATCH];
        const float invf = __builtin_amdgcn_rcpf(f);
        const float e2   = EXP2F(lc * invf);
        const float t1   = __builtin_fmaf(-f, e2, f);
        const float vn   = __builtin_fmaf(av, v, dt_il * f);
        const float qn   = __builtin_fmaf(av, q, kq * t1);
        // canonical (s,f) step — identical to P2
        const float s2 = __builtin_fmaf(as_, s,
                         __builtin_fmaf(dtn, z,
                         __builtin_fmaf(-dtm, f, dtm)));
        f = __builtin_fmaf(DT, s, f);
        s = s2;

        const float invv = __builtin_amdgcn_rcpf(vn);
        const float y = __builtin_fmaf(-c2, qn * invv,
                        __builtin_fmaf(-c3, vn,
                        __builtin_fmaf(-c1, qn, c0)));
        __builtin_nontemporal_store(y, op + j * BATCH);
        v = vn; q = qn;
    }
}

extern "C" void kernel_launch(void* const* d_in, const int* in_sizes, int n_in,
                              void* d_out, int out_size, void* d_ws, size_t ws_size,
                              hipStream_t stream) {
    const float* noise   = (const float*)d_in[0];
    const float* p_sigma = (const float*)d_in[1];
    const float* p_mu    = (const float*)d_in[2];
    const float* p_lamb  = (const float*)d_in[3];
    const float* p_beta  = (const float*)d_in[4];
    const float* p_psi   = (const float*)d_in[5];
    const float* p_phi   = (const float*)d_in[6];
    const float* p_chi   = (const float*)d_in[7];

    balloon_scan<<<BATCH / GSIMS, NTHREADS, 0, stream>>>(
        noise, p_sigma, p_mu, p_lamb, p_beta, p_psi, p_phi, p_chi,
        (float*)d_out);
}

// Round 6
// 162.321 us; speedup vs baseline: 1.2186x; 1.2186x over previous
//
#include <hip/hip_runtime.h>

// Balloon-Windkessel BOLD, explicit Euler, T=1000, B=16384.
// alpha==1 decouples the system: (s,f) is an affine scan with constant 2x2
// matrix A; v,q are affine scans with constant scalar av = 1-DT/lamb. Only
// E(f) is nonlinear (pointwise).
//
// ROUND-6: TWO-KERNEL SPLIT. Six measurements show the monolithic kernel
// alternates memory-phases and compute/barrier-phases in lockstep (phases
// SUM: 47us vs ~25us overlap floor), and its geometry is boxed at 20
// waves/CU. Split through d_ws:
//   Kernel A (stage): 40 chunks x 25 steps, 16 sims/block, 640 thr,
//     grid 1024 (30 waves/CU). P1 (s,f aggregate) -> scan1 -> P2 (v,q
//     aggregates, replay f) -> scan2 -> store chunk-start (s0,f0,v0,q0)
//     float4 to ws (10.5 MB). Cached reads only (r1 proved GSIMS=16
//     CACHED reads don't amplify); full-line float4 store.
//   Kernel B (emit): one thread per (chunk,sim); 256-thr blocks, grid
//     (64,40) = 2560 blocks (32 waves/CU). NO barriers/LDS/scans - pure
//     independent streaming. Replays the 25 steps from stored state,
//     emits y. 256 B/wave loads; NT full-line stores (r5 showed NT
//     partial-line stores amplify 1.8x - avoided here).
// Numerics: identical op sequences to the validated r1 chain; fp32 state
// roundtrips through memory bit-exactly -> absmax unchanged (9.54e-7).
// Fallback: proven r0 monolithic kernel if ws_size < 10.5 MB.

#define BATCH     16384
#define DT        0.01f
#define NOISE_AMP 0.01f
#define V0        0.02f
#define CHUNKS    40
#define CL        25          // 40 * 25 = 1000 steps
#define LANES     16          // sims per block (kernel A)
#define GSIMS     16
#define NTHREADS  (CHUNKS * LANES)   // 640
#define LEVELS    6           // ceil(log2(40))
#define BSIM      256         // kernel-B block size

typedef float f4 __attribute__((ext_vector_type(4)));

#if __has_builtin(__builtin_amdgcn_exp2f)
#define EXP2F(x) __builtin_amdgcn_exp2f(x)
#else
#define EXP2F(x) exp2f(x)
#endif

__device__ __forceinline__ float uf(float x) {
    return __uint_as_float(__builtin_amdgcn_readfirstlane(__float_as_uint(x)));
}

struct D22 { double a, b, c, d; };
__device__ __forceinline__ D22 dmul(D22 x, D22 y) {
    D22 r;
    r.a = x.a * y.a + x.b * y.c;  r.b = x.a * y.b + x.b * y.d;
    r.c = x.c * y.a + x.d * y.c;  r.d = x.c * y.b + x.d * y.d;
    return r;
}

// ---------------------------------------------------------------------------
// Kernel A: per-chunk aggregates + scans; writes chunk-start states to ws.
// ---------------------------------------------------------------------------
__global__ __launch_bounds__(NTHREADS, 8) void balloon_stage(
    const float* __restrict__ noise,
    const float* __restrict__ p_sigma,
    const float* __restrict__ p_mu,
    const float* __restrict__ p_lamb,
    const float* __restrict__ p_beta,
    float* __restrict__ ws)
{
    const int tid = threadIdx.x;
    const int g   = tid & (LANES - 1);   // sim within block
    const int cc  = tid >> 4;            // chunk 0..39
    const int sim = blockIdx.x * GSIMS + g;

    const float sigma = uf(p_sigma[0]);
    const float mu    = uf(p_mu[0]);
    const float lamb  = uf(p_lamb[0]);
    const float beta  = uf(p_beta[0]);

    // ---- uniform fp32 step constants (identical forms to the validated R2) ----
    const float as_   = 1.0f - DT * sigma;
    const float dtn   = DT * NOISE_AMP;
    const float dtm   = DT * mu;
    const float dt_il = uf((float)(0.01 / (double)lamb));
    const float av    = 1.0f - dt_il;
    const float kq    = uf(dt_il / beta);
    const float lc    = uf(log2f(1.0f - beta));

    // ---- chunk-power weights in f64, once: A^(25*2^j), av^(25*2^j) ----
    D22 A; A.a = 1.0 - 0.01 * (double)sigma; A.b = -0.01 * (double)mu;
           A.c = 0.01;                       A.d = 1.0;
    D22 A2 = dmul(A, A), A4 = dmul(A2, A2), A8 = dmul(A4, A4);
    D22 A16 = dmul(A8, A8);
    D22 P = dmul(dmul(A16, A8), A);                 // A^25
    double avd = 1.0 - 0.01 / (double)lamb;
    double av2 = avd * avd, av4 = av2 * av2, av8 = av4 * av4;
    double av16 = av8 * av8;
    double ap = av16 * av8 * avd;                   // av^25

    float M11[LEVELS], M12[LEVELS], M21[LEVELS], M22[LEVELS], AVP[LEVELS];
#pragma unroll
    for (int j = 0; j < LEVELS; ++j) {
        M11[j] = uf((float)P.a); M12[j] = uf((float)P.b);
        M21[j] = uf((float)P.c); M22[j] = uf((float)P.d);
        AVP[j] = uf((float)ap);
        P = dmul(P, P); ap = ap * ap;
    }

    // homogeneous parts at this thread's chunk start: A^(25c)*(0,1), av^(25c)*1
    float ws_h = 0.0f, wf_h = 1.0f, avc = 1.0f;
#pragma unroll
    for (int j = 0; j < LEVELS; ++j) {
        if ((cc >> j) & 1) {
            float t = __builtin_fmaf(M11[j], ws_h, M12[j] * wf_h);
            wf_h = __builtin_fmaf(M21[j], ws_h, M22[j] * wf_h);
            ws_h = t;
            avc *= AVP[j];
        }
    }

    __shared__ float sA[NTHREADS];
    __shared__ float sB[NTHREADS];

    const float* zp = noise + cc * (CL * BATCH) + sim;

    // ---------------- P1: (s,f) chunk aggregate ----------------
    float rs = 0.0f, rf = 0.0f;
#pragma unroll
    for (int j = 0; j < CL; ++j) {
        const float z = zp[j * BATCH];
        const float u = __builtin_fmaf(dtn, z, dtm);
        const float t = __builtin_fmaf(as_, rs, __builtin_fmaf(-dtm, rf, u));
        rf = __builtin_fmaf(DT, rs, rf);
        rs = t;
    }

    // ---------------- scan1: inclusive over chunks, matrix weights ----------------
    sA[tid] = rs; sB[tid] = rf;
    __syncthreads();
#pragma unroll
    for (int j = 0; j < LEVELS; ++j) {
        const int off = 1 << j;
        float ns = 0.0f, nf = 0.0f;
        const bool has = (cc >= off);
        if (has) { ns = sA[tid - off * LANES]; nf = sB[tid - off * LANES]; }
        __syncthreads();
        if (has) {
            rs = __builtin_fmaf(M11[j], ns, __builtin_fmaf(M12[j], nf, rs));
            rf = __builtin_fmaf(M21[j], ns, __builtin_fmaf(M22[j], nf, rf));
            sA[tid] = rs; sB[tid] = rf;
        }
        __syncthreads();
    }
    float s0 = ws_h, f0 = wf_h;
    if (cc > 0) { s0 += sA[tid - LANES]; f0 += sB[tid - LANES]; }
    __syncthreads();   // sA/sB reads done; safe to reuse for scan2

    // ---------------- P2: replay f, accumulate v,q aggregates ----------------
    float s = s0, f = f0, Rv = 0.0f, Rq = 0.0f;
#pragma unroll
    for (int j = 0; j < CL; ++j) {
        const float z    = zp[j * BATCH];
        const float invf = __builtin_amdgcn_rcpf(f);
        const float e2   = EXP2F(lc * invf);
        const float t1   = __builtin_fmaf(-f, e2, f);       // f*E(f)
        Rv = __builtin_fmaf(av, Rv, dt_il * f);
        Rq = __builtin_fmaf(av, Rq, kq * t1);
        // canonical (s,f) step — MUST match kernel B exactly
        const float s2 = __builtin_fmaf(as_, s,
                         __builtin_fmaf(dtn, z,
                         __builtin_fmaf(-dtm, f, dtm)));
        f = __builtin_fmaf(DT, s, f);
        s = s2;
    }

    // ---------------- scan2: scalar weights av^(25*2^j) ----------------
    sA[tid] = Rv; sB[tid] = Rq;
    __syncthreads();
#pragma unroll
    for (int j = 0; j < LEVELS; ++j) {
        const int off = 1 << j;
        float nv = 0.0f, nq = 0.0f;
        const bool has = (cc >= off);
        if (has) { nv = sA[tid - off * LANES]; nq = sB[tid - off * LANES]; }
        __syncthreads();
        if (has) {
            Rv = __builtin_fmaf(AVP[j], nv, Rv);
            Rq = __builtin_fmaf(AVP[j], nq, Rq);
            sA[tid] = Rv; sB[tid] = Rq;
        }
        __syncthreads();
    }
    float v = avc, q = avc;                 // v_init = q_init = 1
    if (cc > 0) { v += sA[tid - LANES]; q += sB[tid - LANES]; }

    // ---------------- store chunk-start state (bit-exact roundtrip) ----------------
    f4 st; st.x = s0; st.y = f0; st.z = v; st.w = q;
    reinterpret_cast<f4*>(ws)[cc * BATCH + sim] = st;
}

// ---------------------------------------------------------------------------
// Kernel B: pure streaming emit — no barriers, no LDS, max TLP.
// ---------------------------------------------------------------------------
__global__ __launch_bounds__(BSIM, 8) void balloon_emit(
    const float* __restrict__ noise,
    const float* __restrict__ p_sigma,
    const float* __restrict__ p_mu,
    const float* __restrict__ p_lamb,
    const float* __restrict__ p_beta,
    const float* __restrict__ p_psi,
    const float* __restrict__ p_phi,
    const float* __restrict__ p_chi,
    const float* __restrict__ ws,
    float* __restrict__ out)
{
    const int cc  = blockIdx.y;                       // chunk 0..39
    const int sim = blockIdx.x * BSIM + threadIdx.x;  // 0..16383

    const float sigma = uf(p_sigma[0]);
    const float mu    = uf(p_mu[0]);
    const float lamb  = uf(p_lamb[0]);
    const float beta  = uf(p_beta[0]);
    const float psi   = uf(p_psi[0]);
    const float phi   = uf(p_phi[0]);
    const float chi   = uf(p_chi[0]);

    const float as_   = 1.0f - DT * sigma;
    const float dtn   = DT * NOISE_AMP;
    const float dtm   = DT * mu;
    const float dt_il = uf((float)(0.01 / (double)lamb));
    const float av    = 1.0f - dt_il;
    const float kq    = uf(dt_il / beta);
    const float lc    = uf(log2f(1.0f - beta));
    const float c0 = V0 * (phi + psi + chi), c1 = V0 * phi, c2 = V0 * psi, c3 = V0 * chi;

    const f4 st = reinterpret_cast<const f4*>(ws)[cc * BATCH + sim];
    float s = st.x, f = st.y, v = st.z, q = st.w;

    const float* zp = noise + cc * (CL * BATCH) + sim;
    float*       op = out   + cc * (CL * BATCH) + sim;

#pragma unroll
    for (int j = 0; j < CL; ++j) {
        const float z    = zp[j * BATCH];
        const float invf = __builtin_amdgcn_rcpf(f);
        const float e2   = EXP2F(lc * invf);
        const float t1   = __builtin_fmaf(-f, e2, f);
        const float vn   = __builtin_fmaf(av, v, dt_il * f);
        const float qn   = __builtin_fmaf(av, q, kq * t1);
        // canonical (s,f) step — identical to kernel A's P2
        const float s2 = __builtin_fmaf(as_, s,
                         __builtin_fmaf(dtn, z,
                         __builtin_fmaf(-dtm, f, dtm)));
        f = __builtin_fmaf(DT, s, f);
        s = s2;

        const float invv = __builtin_amdgcn_rcpf(vn);
        const float y = __builtin_fmaf(-c2, qn * invv,
                        __builtin_fmaf(-c3, vn,
                        __builtin_fmaf(-c1, qn, c0)));
        __builtin_nontemporal_store(y, op + j * BATCH);
        v = vn; q = qn;
    }
}

// ---------------------------------------------------------------------------
// Fallback: proven round-0 monolithic kernel (47us/dispatch), used only if
// ws_size is too small for the state buffer.
// ---------------------------------------------------------------------------
#define CH0   20
#define CL0   50
#define GS0   32
#define NT0   (CH0 * GS0)   // 640

__global__ __launch_bounds__(NT0, 5) void balloon_mono(
    const float* __restrict__ noise,
    const float* __restrict__ p_sigma,
    const float* __restrict__ p_mu,
    const float* __restrict__ p_lamb,
    const float* __restrict__ p_beta,
    const float* __restrict__ p_psi,
    const float* __restrict__ p_phi,
    const float* __restrict__ p_chi,
    float* __restrict__ out)
{
    const int tid = threadIdx.x;
    const int g   = tid & (GS0 - 1);
    const int cc  = tid >> 5;
    const int sim = blockIdx.x * GS0 + g;

    const float sigma = uf(p_sigma[0]);
    const float mu    = uf(p_mu[0]);
    const float lamb  = uf(p_lamb[0]);
    const float beta  = uf(p_beta[0]);
    const float psi   = uf(p_psi[0]);
    const float phi   = uf(p_phi[0]);
    const float chi   = uf(p_chi[0]);

    const float as_   = 1.0f - DT * sigma;
    const float dtn   = DT * NOISE_AMP;
    const float dtm   = DT * mu;
    const float dt_il = uf((float)(0.01 / (double)lamb));
    const float av    = 1.0f - dt_il;
    const float kq    = uf(dt_il / beta);
    const float lc    = uf(log2f(1.0f - beta));
    const float c0 = V0 * (phi + psi + chi), c1 = V0 * phi, c2 = V0 * psi, c3 = V0 * chi;

    D22 A; A.a = 1.0 - 0.01 * (double)sigma; A.b = -0.01 * (double)mu;
           A.c = 0.01;                       A.d = 1.0;
    D22 A2 = dmul(A, A), A4 = dmul(A2, A2), A8 = dmul(A4, A4);
    D22 A16 = dmul(A8, A8), A32 = dmul(A16, A16);
    D22 P = dmul(dmul(A32, A16), A2);               // A^50
    double avd = 1.0 - 0.01 / (double)lamb;
    double av2 = avd * avd, av4 = av2 * av2, av8 = av4 * av4;
    double av16 = av8 * av8, av32 = av16 * av16;
    double ap = av32 * av16 * av2;                  // av^50

    float M11[5], M12[5], M21[5], M22[5], AVP[5];
#pragma unroll
    for (int j = 0; j < 5; ++j) {
        M11[j] = uf((float)P.a); M12[j] = uf((float)P.b);
        M21[j] = uf((float)P.c); M22[j] = uf((float)P.d);
        AVP[j] = uf((float)ap);
        P = dmul(P, P); ap = ap * ap;
    }

    float ws_h = 0.0f, wf_h = 1.0f, avc = 1.0f;
#pragma unroll
    for (int j = 0; j < 5; ++j) {
        if ((cc >> j) & 1) {
            float t = __builtin_fmaf(M11[j], ws_h, M12[j] * wf_h);
            wf_h = __builtin_fmaf(M21[j], ws_h, M22[j] * wf_h);
            ws_h = t;
            avc *= AVP[j];
        }
    }

    __shared__ float sA[NT0];
    __shared__ float sB[NT0];

    const float* zp = noise + cc * (CL0 * BATCH) + sim;

    float rs = 0.0f, rf = 0.0f;
#pragma unroll 10
    for (int j = 0; j < CL0; ++j) {
        const float z = zp[j * BATCH];
        const float u = __builtin_fmaf(dtn, z, dtm);
        const float t = __builtin_fmaf(as_, rs, __builtin_fmaf(-dtm, rf, u));
        rf = __builtin_fmaf(DT, rs, rf);
        rs = t;
    }

    sA[tid] = rs; sB[tid] = rf;
    __syncthreads();
#pragma unroll
    for (int j = 0; j < 5; ++j) {
        const int off = 1 << j;
        float ns = 0.0f, nf = 0.0f;
        const bool has = (cc >= off);
        if (has) { ns = sA[tid - off * GS0]; nf = sB[tid - off * GS0]; }
        __syncthreads();
        if (has) {
            rs = __builtin_fmaf(M11[j], ns, __builtin_fmaf(M12[j], nf, rs));
            rf = __builtin_fmaf(M21[j], ns, __builtin_fmaf(M22[j], nf, rf));
            sA[tid] = rs; sB[tid] = rf;
        }
        __syncthreads();
    }
    float s0 = ws_h, f0 = wf_h;
    if (cc > 0) { s0 += sA[tid - GS0]; f0 += sB[tid - GS0]; }
    __syncthreads();

    float s = s0, f = f0, Rv = 0.0f, Rq = 0.0f;
#pragma unroll 10
    for (int j = 0; j < CL0; ++j) {
        const float z    = zp[j * BATCH];
        const float invf = __builtin_amdgcn_rcpf(f);
        const float e2   = EXP2F(lc * invf);
        const float t1   = __builtin_fmaf(-f, e2, f);
        Rv = __builtin_fmaf(av, Rv, dt_il * f);
        Rq = __builtin_fmaf(av, Rq, kq * t1);
        const float s2 = __builtin_fmaf(as_, s,
                         __builtin_fmaf(dtn, z,
                         __builtin_fmaf(-dtm, f, dtm)));
        f = __builtin_fmaf(DT, s, f);
        s = s2;
    }

    sA[tid] = Rv; sB[tid] = Rq;
    __syncthreads();
#pragma unroll
    for (int j = 0; j < 5; ++j) {
        const int off = 1 << j;
        float nv = 0.0f, nq = 0.0f;
        const bool has = (cc >= off);
        if (has) { nv = sA[tid - off * GS0]; nq = sB[tid - off * GS0]; }
        __syncthreads();
        if (has) {
            Rv = __builtin_fmaf(AVP[j], nv, Rv);
            Rq = __builtin_fmaf(AVP[j], nq, Rq);
            sA[tid] = Rv; sB[tid] = Rq;
        }
        __syncthreads();
    }
    float v = avc, q = avc;
    if (cc > 0) { v += sA[tid - GS0]; q += sB[tid - GS0]; }

    s = s0; f = f0;
    float* op = out + cc * (CL0 * BATCH) + sim;
#pragma unroll 10
    for (int j = 0; j < CL0; ++j) {
        const float z    = zp[j * BATCH];
        const float invf = __builtin_amdgcn_rcpf(f);
        const float e2   = EXP2F(lc * invf);
        const float t1   = __builtin_fmaf(-f, e2, f);
        const float vn   = __builtin_fmaf(av, v, dt_il * f);
        const float qn   = __builtin_fmaf(av, q, kq * t1);
        const float s2 = __builtin_fmaf(as_, s,
                         __builtin_fmaf(dtn, z,
                         __builtin_fmaf(-dtm, f, dtm)));
        f = __builtin_fmaf(DT, s, f);
        s = s2;

        const float invv = __builtin_amdgcn_rcpf(vn);
        const float y = __builtin_fmaf(-c2, qn * invv,
                        __builtin_fmaf(-c3, vn,
                        __builtin_fmaf(-c1, qn, c0)));
        op[j * BATCH] = y;
        v = vn; q = qn;
    }
}

extern "C" void kernel_launch(void* const* d_in, const int* in_sizes, int n_in,
                              void* d_out, int out_size, void* d_ws, size_t ws_size,
                              hipStream_t stream) {
    const float* noise   = (const float*)d_in[0];
    const float* p_sigma = (const float*)d_in[1];
    const float* p_mu    = (const float*)d_in[2];
    const float* p_lamb  = (const float*)d_in[3];
    const float* p_beta  = (const float*)d_in[4];
    const float* p_psi   = (const float*)d_in[5];
    const float* p_phi   = (const float*)d_in[6];
    const float* p_chi   = (const float*)d_in[7];

    const size_t need = (size_t)CHUNKS * BATCH * 4 * sizeof(float);  // 10.5 MB
    if (d_ws != nullptr && ws_size >= need) {
        balloon_stage<<<BATCH / GSIMS, NTHREADS, 0, stream>>>(
            noise, p_sigma, p_mu, p_lamb, p_beta, (float*)d_ws);
        balloon_emit<<<dim3(BATCH / BSIM, CHUNKS), BSIM, 0, stream>>>(
            noise, p_sigma, p_mu, p_lamb, p_beta, p_psi, p_phi, p_chi,
            (const float*)d_ws, (float*)d_out);
    } else {
        balloon_mono<<<BATCH / GS0, NT0, 0, stream>>>(
            noise, p_sigma, p_mu, p_lamb, p_beta, p_psi, p_phi, p_chi,
            (float*)d_out);
    }
}

// Round 7
// 151.000 us; speedup vs baseline: 1.3100x; 1.0750x over previous
//
#include <hip/hip_runtime.h>

// Balloon-Windkessel BOLD, explicit Euler, T=1000, B=16384.
// alpha==1 decouples the system: (s,f) is an affine scan with constant 2x2
// matrix A; v,q are affine scans with constant scalar av = 1-DT/lamb. Only
// E(f) is nonlinear (pointwise).
//
// ROUND-7: FULLY BARRIER-FREE PIPELINE. Round-6 measured: the barrier-
// phased 640-thr stage kernel takes 47us EVEN WITH ALL DATA L3-RESIDENT
// (iters>=2: WRITE=10MB, hbm=210GB/s, still 47us) -> structure-bound, not
// memory-bound. Meanwhile the barrier-free emit kernel (same strided
// loads, heavier epilogue) ran ~7us. So: express EVERYTHING in the
// emit shape. One thread per (chunk,sim), 256-thr flat blocks, no LDS,
// no barriers. The cross-chunk scans become tiny per-sim serial f64
// kernels (40 steps, 5MB traffic) instead of 24 block-wide barriers.
//   k_aggsf : per-(chunk,sim) fp32 (s,f) chunk aggregate -> ws      (64MB rd)
//   k_scansf: per-sim serial f64 affine scan over 40 chunks (A^25)  (5MB)
//   k_aggvq : replay f from (s0,f0); fp32 v,q chunk aggregates -> ws(64MB rd, L3-hot)
//   k_scanvq: per-sim serial f64 scalar scan (av^25)                (5MB)
//   k_emit  : replay f, compute y, NT store                         (64MB rd + 64MB wr)
// Working set (64+64+10MB) fits in 256MB L3 -> steady state runs out of
// L3; HBM roofline irrelevant; latency/issue rules, and barrier-free
// structure is what lets TLP cover it.
// Numerics: within-chunk fp32 ops are token-identical to the validated
// chain; chunk-start states come from serial f64 scans (tighter rounding
// than the previous fp32 Hillis-Steele tree). f trajectory in k_aggvq and
// k_emit is bitwise identical (same fp32 start, same ops).
// Fallback: proven r0 monolithic kernel if ws_size < 10.5 MB.

#define BATCH     16384
#define DT        0.01f
#define NOISE_AMP 0.01f
#define V0        0.02f
#define CHUNKS    40
#define CL        25          // 40 * 25 = 1000 steps
#define TPB       256         // flat block size for streaming kernels

#if __has_builtin(__builtin_amdgcn_exp2f)
#define EXP2F(x) __builtin_amdgcn_exp2f(x)
#else
#define EXP2F(x) exp2f(x)
#endif

__device__ __forceinline__ float uf(float x) {
    return __uint_as_float(__builtin_amdgcn_readfirstlane(__float_as_uint(x)));
}

struct D22 { double a, b, c, d; };
__device__ __forceinline__ D22 dmul(D22 x, D22 y) {
    D22 r;
    r.a = x.a * y.a + x.b * y.c;  r.b = x.a * y.b + x.b * y.d;
    r.c = x.c * y.a + x.d * y.c;  r.d = x.c * y.b + x.d * y.d;
    return r;
}

__device__ __forceinline__ D22 a25_of(float sigma, float mu) {
    D22 A; A.a = 1.0 - 0.01 * (double)sigma; A.b = -0.01 * (double)mu;
           A.c = 0.01;                       A.d = 1.0;
    D22 A2 = dmul(A, A), A4 = dmul(A2, A2), A8 = dmul(A4, A4);
    D22 A16 = dmul(A8, A8);
    return dmul(dmul(A16, A8), A);                  // A^25
}

// ---------------------------------------------------------------------------
// k_aggsf: per-(chunk,sim) fp32 (s,f) chunk aggregate.
// ---------------------------------------------------------------------------
__global__ __launch_bounds__(TPB, 8) void k_aggsf(
    const float* __restrict__ noise,
    const float* __restrict__ p_sigma,
    const float* __restrict__ p_mu,
    float* __restrict__ wsS, float* __restrict__ wsF)
{
    const int sim = blockIdx.x * TPB + threadIdx.x;
    const int cc  = blockIdx.y;

    const float sigma = uf(p_sigma[0]);
    const float mu    = uf(p_mu[0]);
    const float as_   = 1.0f - DT * sigma;
    const float dtn   = DT * NOISE_AMP;
    const float dtm   = DT * mu;

    const float* zp = noise + cc * (CL * BATCH) + sim;
    float rs = 0.0f, rf = 0.0f;
#pragma unroll
    for (int j = 0; j < CL; ++j) {
        const float z = zp[j * BATCH];
        const float u = __builtin_fmaf(dtn, z, dtm);
        const float t = __builtin_fmaf(as_, rs, __builtin_fmaf(-dtm, rf, u));
        rf = __builtin_fmaf(DT, rs, rf);
        rs = t;
    }
    wsS[cc * BATCH + sim] = rs;
    wsF[cc * BATCH + sim] = rf;
}

// ---------------------------------------------------------------------------
// k_scansf: per-sim serial f64 affine scan; overwrites aggregates with
// chunk-START states (state BEFORE applying that chunk's aggregate).
// ---------------------------------------------------------------------------
__global__ __launch_bounds__(TPB, 8) void k_scansf(
    const float* __restrict__ p_sigma,
    const float* __restrict__ p_mu,
    float* __restrict__ wsS, float* __restrict__ wsF)
{
    const int sim = blockIdx.x * TPB + threadIdx.x;
    const D22 P = a25_of(uf(p_sigma[0]), uf(p_mu[0]));

    double s = 0.0, f = 1.0;   // state at t=0
#pragma unroll 8
    for (int c = 0; c < CHUNKS; ++c) {
        const int idx = c * BATCH + sim;
        const float rs = wsS[idx], rf = wsF[idx];
        wsS[idx] = (float)s; wsF[idx] = (float)f;
        const double ns = P.a * s + P.b * f + (double)rs;
        f               = P.c * s + P.d * f + (double)rf;
        s = ns;
    }
}

// ---------------------------------------------------------------------------
// k_aggvq: replay f from fp32 (s0,f0); fp32 v,q chunk aggregates.
// ---------------------------------------------------------------------------
__global__ __launch_bounds__(TPB, 8) void k_aggvq(
    const float* __restrict__ noise,
    const float* __restrict__ p_sigma,
    const float* __restrict__ p_mu,
    const float* __restrict__ p_lamb,
    const float* __restrict__ p_beta,
    const float* __restrict__ wsS, const float* __restrict__ wsF,
    float* __restrict__ wsV, float* __restrict__ wsQ)
{
    const int sim = blockIdx.x * TPB + threadIdx.x;
    const int cc  = blockIdx.y;

    const float sigma = uf(p_sigma[0]);
    const float mu    = uf(p_mu[0]);
    const float lamb  = uf(p_lamb[0]);
    const float beta  = uf(p_beta[0]);

    const float as_   = 1.0f - DT * sigma;
    const float dtn   = DT * NOISE_AMP;
    const float dtm   = DT * mu;
    const float dt_il = uf((float)(0.01 / (double)lamb));
    const float av    = 1.0f - dt_il;
    const float kq    = uf(dt_il / beta);
    const float lc    = uf(log2f(1.0f - beta));

    float s = wsS[cc * BATCH + sim];
    float f = wsF[cc * BATCH + sim];

    const float* zp = noise + cc * (CL * BATCH) + sim;
    float Rv = 0.0f, Rq = 0.0f;
#pragma unroll
    for (int j = 0; j < CL; ++j) {
        const float z    = zp[j * BATCH];
        const float invf = __builtin_amdgcn_rcpf(f);
        const float e2   = EXP2F(lc * invf);
        const float t1   = __builtin_fmaf(-f, e2, f);       // f*E(f)
        Rv = __builtin_fmaf(av, Rv, dt_il * f);
        Rq = __builtin_fmaf(av, Rq, kq * t1);
        // canonical (s,f) step — MUST match k_emit exactly
        const float s2 = __builtin_fmaf(as_, s,
                         __builtin_fmaf(dtn, z,
                         __builtin_fmaf(-dtm, f, dtm)));
        f = __builtin_fmaf(DT, s, f);
        s = s2;
    }
    wsV[cc * BATCH + sim] = Rv;
    wsQ[cc * BATCH + sim] = Rq;
}

// ---------------------------------------------------------------------------
// k_scanvq: per-sim serial f64 scalar scan (av^25); aggregates -> starts.
// ---------------------------------------------------------------------------
__global__ __launch_bounds__(TPB, 8) void k_scanvq(
    const float* __restrict__ p_lamb,
    float* __restrict__ wsV, float* __restrict__ wsQ)
{
    const int sim = blockIdx.x * TPB + threadIdx.x;
    const double avd = 1.0 - 0.01 / (double)uf(p_lamb[0]);
    const double av2 = avd * avd, av4 = av2 * av2, av8 = av4 * av4;
    const double av16 = av8 * av8;
    const double ap = av16 * av8 * avd;                 // av^25

    double v = 1.0, q = 1.0;   // state at t=0
#pragma unroll 8
    for (int c = 0; c < CHUNKS; ++c) {
        const int idx = c * BATCH + sim;
        const float Rv = wsV[idx], Rq = wsQ[idx];
        wsV[idx] = (float)v; wsQ[idx] = (float)q;
        v = ap * v + (double)Rv;
        q = ap * q + (double)Rq;
    }
}

// ---------------------------------------------------------------------------
// k_emit: replay f, compute y, NT store. (Proven ~7us shape in round 6.)
// ---------------------------------------------------------------------------
__global__ __launch_bounds__(TPB, 8) void k_emit(
    const float* __restrict__ noise,
    const float* __restrict__ p_sigma,
    const float* __restrict__ p_mu,
    const float* __restrict__ p_lamb,
    const float* __restrict__ p_beta,
    const float* __restrict__ p_psi,
    const float* __restrict__ p_phi,
    const float* __restrict__ p_chi,
    const float* __restrict__ wsS, const float* __restrict__ wsF,
    const float* __restrict__ wsV, const float* __restrict__ wsQ,
    float* __restrict__ out)
{
    const int sim = blockIdx.x * TPB + threadIdx.x;
    const int cc  = blockIdx.y;

    const float sigma = uf(p_sigma[0]);
    const float mu    = uf(p_mu[0]);
    const float lamb  = uf(p_lamb[0]);
    const float beta  = uf(p_beta[0]);
    const float psi   = uf(p_psi[0]);
    const float phi   = uf(p_phi[0]);
    const float chi   = uf(p_chi[0]);

    const float as_   = 1.0f - DT * sigma;
    const float dtn   = DT * NOISE_AMP;
    const float dtm   = DT * mu;
    const float dt_il = uf((float)(0.01 / (double)lamb));
    const float av    = 1.0f - dt_il;
    const float kq    = uf(dt_il / beta);
    const float lc    = uf(log2f(1.0f - beta));
    const float c0 = V0 * (phi + psi + chi), c1 = V0 * phi, c2 = V0 * psi, c3 = V0 * chi;

    float s = wsS[cc * BATCH + sim];
    float f = wsF[cc * BATCH + sim];
    float v = wsV[cc * BATCH + sim];
    float q = wsQ[cc * BATCH + sim];

    const float* zp = noise + cc * (CL * BATCH) + sim;
    float*       op = out   + cc * (CL * BATCH) + sim;

#pragma unroll
    for (int j = 0; j < CL; ++j) {
        const float z    = zp[j * BATCH];
        const float invf = __builtin_amdgcn_rcpf(f);
        const float e2   = EXP2F(lc * invf);
        const float t1   = __builtin_fmaf(-f, e2, f);
        const float vn   = __builtin_fmaf(av, v, dt_il * f);
        const float qn   = __builtin_fmaf(av, q, kq * t1);
        // canonical (s,f) step — identical to k_aggvq
        const float s2 = __builtin_fmaf(as_, s,
                         __builtin_fmaf(dtn, z,
                         __builtin_fmaf(-dtm, f, dtm)));
        f = __builtin_fmaf(DT, s, f);
        s = s2;

        const float invv = __builtin_amdgcn_rcpf(vn);
        const float y = __builtin_fmaf(-c2, qn * invv,
                        __builtin_fmaf(-c3, vn,
                        __builtin_fmaf(-c1, qn, c0)));
        __builtin_nontemporal_store(y, op + j * BATCH);
        v = vn; q = qn;
    }
}

// ---------------------------------------------------------------------------
// Fallback: proven round-0 monolithic kernel (47us/dispatch).
// ---------------------------------------------------------------------------
#define CH0   20
#define CL0   50
#define GS0   32
#define NT0   (CH0 * GS0)   // 640

__global__ __launch_bounds__(NT0, 5) void balloon_mono(
    const float* __restrict__ noise,
    const float* __restrict__ p_sigma,
    const float* __restrict__ p_mu,
    const float* __restrict__ p_lamb,
    const float* __restrict__ p_beta,
    const float* __restrict__ p_psi,
    const float* __restrict__ p_phi,
    const float* __restrict__ p_chi,
    float* __restrict__ out)
{
    const int tid = threadIdx.x;
    const int g   = tid & (GS0 - 1);
    const int cc  = tid >> 5;
    const int sim = blockIdx.x * GS0 + g;

    const float sigma = uf(p_sigma[0]);
    const float mu    = uf(p_mu[0]);
    const float lamb  = uf(p_lamb[0]);
    const float beta  = uf(p_beta[0]);
    const float psi   = uf(p_psi[0]);
    const float phi   = uf(p_phi[0]);
    const float chi   = uf(p_chi[0]);

    const float as_   = 1.0f - DT * sigma;
    const float dtn   = DT * NOISE_AMP;
    const float dtm   = DT * mu;
    const float dt_il = uf((float)(0.01 / (double)lamb));
    const float av    = 1.0f - dt_il;
    const float kq    = uf(dt_il / beta);
    const float lc    = uf(log2f(1.0f - beta));
    const float c0 = V0 * (phi + psi + chi), c1 = V0 * phi, c2 = V0 * psi, c3 = V0 * chi;

    D22 A; A.a = 1.0 - 0.01 * (double)sigma; A.b = -0.01 * (double)mu;
           A.c = 0.01;                       A.d = 1.0;
    D22 A2 = dmul(A, A), A4 = dmul(A2, A2), A8 = dmul(A4, A4);
    D22 A16 = dmul(A8, A8), A32 = dmul(A16, A16);
    D22 P = dmul(dmul(A32, A16), A2);               // A^50
    double avd = 1.0 - 0.01 / (double)lamb;
    double av2 = avd * avd, av4 = av2 * av2, av8 = av4 * av4;
    double av16 = av8 * av8, av32 = av16 * av16;
    double ap = av32 * av16 * av2;                  // av^50

    float M11[5], M12[5], M21[5], M22[5], AVP[5];
#pragma unroll
    for (int j = 0; j < 5; ++j) {
        M11[j] = uf((float)P.a); M12[j] = uf((float)P.b);
        M21[j] = uf((float)P.c); M22[j] = uf((float)P.d);
        AVP[j] = uf((float)ap);
        P = dmul(P, P); ap = ap * ap;
    }

    float ws_h = 0.0f, wf_h = 1.0f, avc = 1.0f;
#pragma unroll
    for (int j = 0; j < 5; ++j) {
        if ((cc >> j) & 1) {
            float t = __builtin_fmaf(M11[j], ws_h, M12[j] * wf_h);
            wf_h = __builtin_fmaf(M21[j], ws_h, M22[j] * wf_h);
            ws_h = t;
            avc *= AVP[j];
        }
    }

    __shared__ float sA[NT0];
    __shared__ float sB[NT0];

    const float* zp = noise + cc * (CL0 * BATCH) + sim;

    float rs = 0.0f, rf = 0.0f;
#pragma unroll 10
    for (int j = 0; j < CL0; ++j) {
        const float z = zp[j * BATCH];
        const float u = __builtin_fmaf(dtn, z, dtm);
        const float t = __builtin_fmaf(as_, rs, __builtin_fmaf(-dtm, rf, u));
        rf = __builtin_fmaf(DT, rs, rf);
        rs = t;
    }

    sA[tid] = rs; sB[tid] = rf;
    __syncthreads();
#pragma unroll
    for (int j = 0; j < 5; ++j) {
        const int off = 1 << j;
        float ns = 0.0f, nf = 0.0f;
        const bool has = (cc >= off);
        if (has) { ns = sA[tid - off * GS0]; nf = sB[tid - off * GS0]; }
        __syncthreads();
        if (has) {
            rs = __builtin_fmaf(M11[j], ns, __builtin_fmaf(M12[j], nf, rs));
            rf = __builtin_fmaf(M21[j], ns, __builtin_fmaf(M22[j], nf, rf));
            sA[tid] = rs; sB[tid] = rf;
        }
        __syncthreads();
    }
    float s0 = ws_h, f0 = wf_h;
    if (cc > 0) { s0 += sA[tid - GS0]; f0 += sB[tid - GS0]; }
    __syncthreads();

    float s = s0, f = f0, Rv = 0.0f, Rq = 0.0f;
#pragma unroll 10
    for (int j = 0; j < CL0; ++j) {
        const float z    = zp[j * BATCH];
        const float invf = __builtin_amdgcn_rcpf(f);
        const float e2   = EXP2F(lc * invf);
        const float t1   = __builtin_fmaf(-f, e2, f);
        Rv = __builtin_fmaf(av, Rv, dt_il * f);
        Rq = __builtin_fmaf(av, Rq, kq * t1);
        const float s2 = __builtin_fmaf(as_, s,
                         __builtin_fmaf(dtn, z,
                         __builtin_fmaf(-dtm, f, dtm)));
        f = __builtin_fmaf(DT, s, f);
        s = s2;
    }

    sA[tid] = Rv; sB[tid] = Rq;
    __syncthreads();
#pragma unroll
    for (int j = 0; j < 5; ++j) {
        const int off = 1 << j;
        float nv = 0.0f, nq = 0.0f;
        const bool has = (cc >= off);
        if (has) { nv = sA[tid - off * GS0]; nq = sB[tid - off * GS0]; }
        __syncthreads();
        if (has) {
            Rv = __builtin_fmaf(AVP[j], nv, Rv);
            Rq = __builtin_fmaf(AVP[j], nq, Rq);
            sA[tid] = Rv; sB[tid] = Rq;
        }
        __syncthreads();
    }
    float v = avc, q = avc;
    if (cc > 0) { v += sA[tid - GS0]; q += sB[tid - GS0]; }

    s = s0; f = f0;
    float* op = out + cc * (CL0 * BATCH) + sim;
#pragma unroll 10
    for (int j = 0; j < CL0; ++j) {
        const float z    = zp[j * BATCH];
        const float invf = __builtin_amdgcn_rcpf(f);
        const float e2   = EXP2F(lc * invf);
        const float t1   = __builtin_fmaf(-f, e2, f);
        const float vn   = __builtin_fmaf(av, v, dt_il * f);
        const float qn   = __builtin_fmaf(av, q, kq * t1);
        const float s2 = __builtin_fmaf(as_, s,
                         __builtin_fmaf(dtn, z,
                         __builtin_fmaf(-dtm, f, dtm)));
        f = __builtin_fmaf(DT, s, f);
        s = s2;

        const float invv = __builtin_amdgcn_rcpf(vn);
        const float y = __builtin_fmaf(-c2, qn * invv,
                        __builtin_fmaf(-c3, vn,
                        __builtin_fmaf(-c1, qn, c0)));
        op[j * BATCH] = y;
        v = vn; q = qn;
    }
}

extern "C" void kernel_launch(void* const* d_in, const int* in_sizes, int n_in,
                              void* d_out, int out_size, void* d_ws, size_t ws_size,
                              hipStream_t stream) {
    const float* noise   = (const float*)d_in[0];
    const float* p_sigma = (const float*)d_in[1];
    const float* p_mu    = (const float*)d_in[2];
    const float* p_lamb  = (const float*)d_in[3];
    const float* p_beta  = (const float*)d_in[4];
    const float* p_psi   = (const float*)d_in[5];
    const float* p_phi   = (const float*)d_in[6];
    const float* p_chi   = (const float*)d_in[7];

    const size_t narr = (size_t)CHUNKS * BATCH;            // 655360 floats
    const size_t need = 4 * narr * sizeof(float);          // 10.5 MB
    if (d_ws != nullptr && ws_size >= need) {
        float* wsS = (float*)d_ws;
        float* wsF = wsS + narr;
        float* wsV = wsF + narr;
        float* wsQ = wsV + narr;

        const dim3 gStream(BATCH / TPB, CHUNKS);           // 64 x 40 blocks
        const int  gScan = BATCH / TPB;                    // 64 blocks

        k_aggsf<<<gStream, TPB, 0, stream>>>(noise, p_sigma, p_mu, wsS, wsF);
        k_scansf<<<gScan, TPB, 0, stream>>>(p_sigma, p_mu, wsS, wsF);
        k_aggvq<<<gStream, TPB, 0, stream>>>(noise, p_sigma, p_mu, p_lamb, p_beta,
                                             wsS, wsF, wsV, wsQ);
        k_scanvq<<<gScan, TPB, 0, stream>>>(p_lamb, wsV, wsQ);
        k_emit<<<gStream, TPB, 0, stream>>>(noise, p_sigma, p_mu, p_lamb, p_beta,
                                            p_psi, p_phi, p_chi,
                                            wsS, wsF, wsV, wsQ, (float*)d_out);
    } else {
        balloon_mono<<<BATCH / GS0, NT0, 0, stream>>>(
            noise, p_sigma, p_mu, p_lamb, p_beta, p_psi, p_phi, p_chi,
            (float*)d_out);
    }
}